// Round 19
// baseline (170.335 us; speedup 1.0000x reference)
//
#include <hip/hip_runtime.h>
#include <math.h>

#define B_   256
#define S_   200
#define NQ_  400
#define K_   4
#define M_   50
#define KD_  50
#define VD_  200
#define FD_  50
#define T_   (B_*S_)   // 51200 tokens
#define NE_  ((NQ_+1)*K_)   // 1604 distinct (q,r) rows
#define CP_  52             // padded clut row stride (16B-aligned rows)

// ---------------------------------------------------------------------------
// kA1: corr LUT, PADDED rows [401][52] (cols 50,51 zeroed).
// ---------------------------------------------------------------------------
__global__ __launch_bounds__(256) void kA1_corrlut(
    const float* __restrict__ q_tab, const float* __restrict__ key_mem,
    const float* __restrict__ W_qk, const float* __restrict__ b_qk,
    float* __restrict__ clutP)
{
    const int wave = threadIdx.x >> 6;
    const int lane = threadIdx.x & 63;
    int qi = blockIdx.x * 4 + wave;
    const bool valid = (qi <= NQ_);
    if (qi > NQ_) qi = NQ_;

    __shared__ float sqk[4][KD_];
    const float* qe = q_tab + (size_t)qi * KD_;
    if (lane < KD_) {
        float acc = b_qk[lane];
#pragma unroll 10
        for (int k = 0; k < KD_; ++k)
            acc += qe[k] * W_qk[k * KD_ + lane];
        sqk[wave][lane] = tanhf(acc);
    }
    __syncthreads();

    float c = -INFINITY;
    if (lane < M_) {
        float acc = 0.0f;
#pragma unroll 10
        for (int k = 0; k < KD_; ++k)
            acc += sqk[wave][k] * key_mem[lane * KD_ + k];
        c = acc;
    }
    float mx = c;
#pragma unroll
    for (int off = 32; off; off >>= 1) mx = fmaxf(mx, __shfl_xor(mx, off));
    float e = (lane < M_) ? expf(c - mx) : 0.0f;
    float sm = e;
#pragma unroll
    for (int off = 32; off; off >>= 1) sm += __shfl_xor(sm, off);
    if (valid && lane < M_)  clutP[(size_t)qi * CP_ + lane] = e / sm;
    if (valid && lane >= M_ && lane < CP_) clutP[(size_t)qi * CP_ + lane] = 0.0f;
}

// ---------------------------------------------------------------------------
// kA2: fused (e,a) LUT as float2 [1604][200]. One block per q, 4 r-variants.
// ---------------------------------------------------------------------------
__global__ __launch_bounds__(256) void kA2_ealut(
    const float* __restrict__ W_v3, const float* __restrict__ b_v,
    const float* __restrict__ W_e, const float* __restrict__ b_e,
    const float* __restrict__ W_a, const float* __restrict__ b_a,
    float2* __restrict__ ea2)
{
    __shared__ __align__(16) float sV[VD_][4];   // [k][r]
    const int qi  = blockIdx.x;                  // 0..400
    const int tid = threadIdx.x;
    const float qm = (qi > 0) ? 1.0f : 0.0f;
    int idx = qi - 1;
    if (idx < 0) idx = 0;

    float wc[4][4];
#pragma unroll
    for (int r = 0; r < 4; ++r)
#pragma unroll
        for (int k = 0; k < 4; ++k) {
            float dist = fabsf((float)k - (float)r) / (float)(K_ - 1);
            float w = 1.0f - dist;
            wc[r][k] = (w > 0.0f) ? w : 0.0f;
        }

    if (tid < VD_) {
        float w3[4];
#pragma unroll
        for (int k = 0; k < 4; ++k)
            w3[k] = W_v3[((size_t)k * NQ_ + idx) * VD_ + tid];
        float bv = b_v[tid];
#pragma unroll
        for (int r = 0; r < 4; ++r) {
            float s = wc[r][0]*w3[0] + wc[r][1]*w3[1] + wc[r][2]*w3[2] + wc[r][3]*w3[3];
            sV[tid][r] = bv + qm * s;
        }
    }
    __syncthreads();

    if (tid < VD_) {
        const int c = tid;
        float accE[4] = {0.f,0.f,0.f,0.f}, accA[4] = {0.f,0.f,0.f,0.f};
#pragma unroll 4
        for (int k = 0; k < VD_; ++k) {
            float we = W_e[(size_t)k * VD_ + c];
            float wa = W_a[(size_t)k * VD_ + c];
            float4 v = *(const float4*)&sV[k][0];
            float vv[4] = {v.x, v.y, v.z, v.w};
#pragma unroll
            for (int r = 0; r < 4; ++r) {
                accE[r] = fmaf(vv[r], we, accE[r]);
                accA[r] = fmaf(vv[r], wa, accA[r]);
            }
        }
        const float be = b_e[c], ba = b_a[c];
#pragma unroll
        for (int r = 0; r < 4; ++r) {
            const size_t row = (size_t)qi * K_ + r;
            float ev = 1.0f / (1.0f + expf(-(accE[r] + be)));
            float av = tanhf(accA[r] + ba);
            ea2[row * VD_ + c] = make_float2(ev, av);
        }
    }
}

// ---------------------------------------------------------------------------
// kB v16 (UNCHANGED — declared floor ~102us): zero-barrier scan, deep (e,a)
// register banks, w via LDS wall + parity register banks.
// ---------------------------------------------------------------------------
__global__ __launch_bounds__(256, 1) void kB_scan(
    const int* __restrict__ q_data, const int* __restrict__ r_data,
    const float* __restrict__ init_mem, const float* __restrict__ clutP,
    const float2* __restrict__ ea2, float* __restrict__ reads)
{
    const int b   = blockIdx.x;
    const int tid = threadIdx.x;
    const int j   = tid;
    const bool act = (j < VD_);

    __shared__ int sE[S_];
    __shared__ __align__(16) float wall[S_][CP_];

    for (int i = tid; i < S_; i += 256)
        sE[i] = q_data[(size_t)b * S_ + i] * K_ + r_data[(size_t)b * S_ + i];
    __syncthreads();
    for (int i = tid; i < S_ * CP_; i += 256) {
        int row = i / CP_, col = i - row * CP_;
        wall[row][col] = clutP[(size_t)(sE[row] >> 2) * CP_ + col];
    }
    float mem[M_];
    if (act) {
#pragma unroll
        for (int m = 0; m < M_; ++m) mem[m] = init_mem[m * VD_ + j];
    }
    __syncthreads();   // LAST barrier

    float* rout = reads + (size_t)b * S_ * VD_;

    float eA[8], aA[8], eB[8], aB[8];
    if (act) {
#pragma unroll
        for (int h = 0; h < 8; ++h) {
            float2 v = ea2[(size_t)sE[h] * VD_ + j];
            eA[h] = v.x; aA[h] = v.y;
        }
#pragma unroll
        for (int h = 0; h < 8; ++h) {
            float2 v = ea2[(size_t)sE[8 + h] * VD_ + j];
            eB[h] = v.x; aB[h] = v.y;
        }
    }

    float4 wv0[13], wv1[13];
#pragma unroll
    for (int i = 0; i < 13; ++i) {
        wv0[i] = *(const float4*)&wall[0][4*i];
        wv1[i] = *(const float4*)&wall[1][4*i];
    }

#define SCAN_STEP(ST, EV, AV, WB)                                    \
    {                                                                \
        float ra = 0.f, rc = 0.f;                                    \
        _Pragma("unroll")                                            \
        for (int i_ = 0; i_ < 12; ++i_) {                            \
            const int m_ = 4 * i_;                                   \
            float4 w4 = WB[i_];                                      \
            ra = fmaf(w4.x, mem[m_], ra);                            \
            float t0 = fmaf(-(EV), mem[m_], (AV));                   \
            mem[m_] = fmaf(w4.x, t0, mem[m_]);                       \
            rc = fmaf(w4.y, mem[m_+1], rc);                          \
            float t1 = fmaf(-(EV), mem[m_+1], (AV));                 \
            mem[m_+1] = fmaf(w4.y, t1, mem[m_+1]);                   \
            ra = fmaf(w4.z, mem[m_+2], ra);                          \
            float t2 = fmaf(-(EV), mem[m_+2], (AV));                 \
            mem[m_+2] = fmaf(w4.z, t2, mem[m_+2]);                   \
            rc = fmaf(w4.w, mem[m_+3], rc);                          \
            float t3 = fmaf(-(EV), mem[m_+3], (AV));                 \
            mem[m_+3] = fmaf(w4.w, t3, mem[m_+3]);                   \
        }                                                            \
        {                                                            \
            float4 w4 = WB[12];                                      \
            ra = fmaf(w4.x, mem[48], ra);                            \
            float t0 = fmaf(-(EV), mem[48], (AV));                   \
            mem[48] = fmaf(w4.x, t0, mem[48]);                       \
            rc = fmaf(w4.y, mem[49], rc);                            \
            float t1 = fmaf(-(EV), mem[49], (AV));                   \
            mem[49] = fmaf(w4.y, t1, mem[49]);                       \
        }                                                            \
        if (act) rout[(size_t)(ST) * VD_ + j] = ra + rc;             \
        {                                                            \
            const int nr_ = ((ST) + 2 < S_) ? (ST) + 2 : S_ - 1;     \
            const float* wr_ = &wall[nr_][0];                        \
            _Pragma("unroll")                                        \
            for (int i_ = 0; i_ < 13; ++i_)                          \
                WB[i_] = *(const float4*)(wr_ + 4 * i_);             \
        }                                                            \
    }

    for (int k = 0; k < 12; ++k) {
        const int s0 = 16 * k;
        int eidAn[8];
#pragma unroll
        for (int h = 0; h < 8; ++h) {
            int idx = s0 + 16 + h; if (idx > S_ - 1) idx = S_ - 1;
            eidAn[h] = sE[idx];
        }
#pragma unroll
        for (int h = 0; h < 8; ++h) {
            if ((h & 1) == 0) { SCAN_STEP(s0 + h, eA[h], aA[h], wv0); }
            else              { SCAN_STEP(s0 + h, eA[h], aA[h], wv1); }
        }
        if (act) {
#pragma unroll
            for (int h = 0; h < 8; ++h) {
                float2 v = ea2[(size_t)eidAn[h] * VD_ + j];
                eA[h] = v.x; aA[h] = v.y;
            }
        }

        int eidBn[8];
#pragma unroll
        for (int h = 0; h < 8; ++h) {
            int idx = s0 + 24 + h; if (idx > S_ - 1) idx = S_ - 1;
            eidBn[h] = sE[idx];
        }
#pragma unroll
        for (int h = 0; h < 8; ++h) {
            if ((h & 1) == 0) { SCAN_STEP(s0 + 8 + h, eB[h], aB[h], wv0); }
            else              { SCAN_STEP(s0 + 8 + h, eB[h], aB[h], wv1); }
        }
        if (act) {
#pragma unroll
            for (int h = 0; h < 8; ++h) {
                float2 v = ea2[(size_t)eidBn[h] * VD_ + j];
                eB[h] = v.x; aB[h] = v.y;
            }
        }
    }
#pragma unroll
    for (int h = 0; h < 8; ++h) {
        if ((h & 1) == 0) { SCAN_STEP(192 + h, eA[h], aA[h], wv0); }
        else              { SCAN_STEP(192 + h, eA[h], aA[h], wv1); }
    }
#undef SCAN_STEP
}

// ---------------------------------------------------------------------------
// k4 (fused): summary GEMM + head, one kernel. Summary stays in LDS (sSum);
// head phase = 4 waves x 10 tokens, lanes 0..49 + shfl-xor reduce, lane 0
// writes the 4 probs. Kills summT round-trip (20 MB) + the k4b launch.
// ---------------------------------------------------------------------------
#define BT4A 40
__global__ __launch_bounds__(256) void k4_fused(
    const int* __restrict__ q_data, const float* __restrict__ q_tab,
    const float* __restrict__ reads,
    const float* __restrict__ W_sum, const float* __restrict__ b_sum,
    const float* __restrict__ W_ab, const float* __restrict__ b_ab,
    const float* __restrict__ W_th, const float* __restrict__ b_th,
    const float* __restrict__ W_disc, const float* __restrict__ b_disc,
    float* __restrict__ out)
{
    __shared__ __align__(16) float sAt[25][44];    // [kk][t], pad 44
    __shared__ __align__(16) float sW[25][52];
    __shared__ __align__(16) float sSum[BT4A][52]; // summary rows
    __shared__ int sQ[BT4A];

    const int tid  = threadIdx.x;
    const int tok0 = blockIdx.x * BT4A;
    const int ty = tid / 25;        // 0..9 -> token group of 4
    const int tx = tid % 25;        // col pair
    const bool act = (tid < 250);
    const int t0 = ty * 4;

    if (tid < BT4A) sQ[tid] = q_data[tok0 + tid];

    float acc[4][2];
#pragma unroll
    for (int i = 0; i < 4; ++i) { acc[i][0] = 0.f; acc[i][1] = 0.f; }

    for (int kt = 0; kt < 250; kt += 25) {
        __syncthreads();
        for (int i = tid; i < BT4A * 25; i += 256) {
            int t = i / 25, kk = i % 25;
            float v;
            if (kt < VD_) v = reads[(size_t)(tok0 + t) * VD_ + kt + kk];
            else          v = q_tab[(size_t)sQ[t] * KD_ + (kt - VD_) + kk];
            sAt[kk][t] = v;
        }
        for (int i = tid; i < 25 * FD_; i += 256) {
            int kk = i / FD_, col = i % FD_;
            sW[kk][col] = W_sum[(size_t)(kt + kk) * FD_ + col];
        }
        __syncthreads();

        if (act) {
#pragma unroll 5
            for (int kk = 0; kk < 25; ++kk) {
                float2 w = *(const float2*)&sW[kk][2 * tx];
                float4 a0 = *(const float4*)&sAt[kk][t0];
                float av[4] = {a0.x, a0.y, a0.z, a0.w};
#pragma unroll
                for (int i = 0; i < 4; ++i) {
                    acc[i][0] = fmaf(av[i], w.x, acc[i][0]);
                    acc[i][1] = fmaf(av[i], w.y, acc[i][1]);
                }
            }
        }
    }

    // summary -> LDS (not global)
    if (act) {
        const float b0 = b_sum[2 * tx], b1 = b_sum[2 * tx + 1];
#pragma unroll
        for (int i = 0; i < 4; ++i) {
            sSum[t0 + i][2 * tx]     = tanhf(acc[i][0] + b0);
            sSum[t0 + i][2 * tx + 1] = tanhf(acc[i][1] + b1);
        }
    }
    __syncthreads();

    // head phase: wave w handles tokens w*10 .. w*10+9
    const int wv   = tid >> 6;
    const int lane = tid & 63;
    for (int lt = wv * 10; lt < wv * 10 + 10; ++lt) {
        const int tok = tok0 + lt;
        const float s  = (lane < FD_) ? sSum[lt][lane] : 0.0f;
        const int  qi  = sQ[lt];
        const float qv = (lane < KD_) ? q_tab[(size_t)qi * KD_ + lane] : 0.0f;

        float v_ab = (lane < FD_) ? s * W_ab[lane] : 0.0f;
        float v_d  = ((lane < FD_) ? s * W_disc[lane] : 0.0f)
                   + ((lane < KD_) ? qv * W_disc[FD_ + lane] : 0.0f);
        float v_t0 = (lane < KD_) ? qv * W_th[lane * 3 + 0] : 0.0f;
        float v_t1 = (lane < KD_) ? qv * W_th[lane * 3 + 1] : 0.0f;
        float v_t2 = (lane < KD_) ? qv * W_th[lane * 3 + 2] : 0.0f;

#pragma unroll
        for (int off = 32; off; off >>= 1) {
            v_ab += __shfl_xor(v_ab, off);
            v_d  += __shfl_xor(v_d,  off);
            v_t0 += __shfl_xor(v_t0, off);
            v_t1 += __shfl_xor(v_t1, off);
            v_t2 += __shfl_xor(v_t2, off);
        }

        if (lane == 0) {
            float theta = 3.0f * (v_ab + b_ab[0]);
            float xd = v_d + b_disc[0];
            float alpha = fmaxf(xd, 0.0f) + log1pf(expf(-fabsf(xd)));
            float beta0 = tanhf(v_t0 + b_th[0]);
            float beta1 = tanhf(v_t1 + b_th[1]);
            float beta2 = tanhf(v_t2 + b_th[2]);
            float c1 = alpha * (theta - beta0);
            float c2 = c1 + alpha * (theta - beta1);
            float c3 = c2 + alpha * (theta - beta2);
            float mx = fmaxf(fmaxf(0.0f, c1), fmaxf(c2, c3));
            float e0 = expf(0.0f - mx), e1 = expf(c1 - mx),
                  e2 = expf(c2 - mx), e3 = expf(c3 - mx);
            float s4 = e0 + e1 + e2 + e3;
            float4 o = make_float4(e0 / s4, e1 / s4, e2 / s4, e3 / s4);
            *(float4*)&out[(size_t)tok * 4] = o;
        }
    }
}

// ---------------------------------------------------------------------------
extern "C" void kernel_launch(void* const* d_in, const int* in_sizes, int n_in,
                              void* d_out, int out_size, void* d_ws, size_t ws_size,
                              hipStream_t stream) {
    const int*   q_data   = (const int*)  d_in[0];
    const int*   r_data   = (const int*)  d_in[1];
    const float* q_tab    = (const float*)d_in[2];
    const float* key_mem  = (const float*)d_in[3];
    const float* init_mem = (const float*)d_in[4];
    const float* W_qk     = (const float*)d_in[5];
    const float* b_qk     = (const float*)d_in[6];
    const float* W_v3     = (const float*)d_in[7];
    const float* b_v      = (const float*)d_in[8];
    const float* W_e      = (const float*)d_in[9];
    const float* b_e      = (const float*)d_in[10];
    const float* W_a      = (const float*)d_in[11];
    const float* b_a      = (const float*)d_in[12];
    const float* W_sum    = (const float*)d_in[13];
    const float* b_sum    = (const float*)d_in[14];
    const float* W_ab     = (const float*)d_in[15];
    const float* b_ab     = (const float*)d_in[16];
    const float* W_th     = (const float*)d_in[17];
    const float* b_th     = (const float*)d_in[18];
    const float* W_disc   = (const float*)d_in[19];
    const float* b_disc   = (const float*)d_in[20];

    float* ws    = (float*)d_ws;
    float* reads = ws;                                    // T*VD = 10.24M
    float* clutP = reads + (size_t)T_ * VD_;              // 401*52
    float* ea2f  = clutP + (size_t)(NQ_ + 1) * CP_;       // 1604*200*2 (float2)
    // total ~10.9M floats = 44 MB

    kA1_corrlut<<<(NQ_ + 4) / 4, 256, 0, stream>>>(q_tab, key_mem, W_qk, b_qk, clutP);
    kA2_ealut<<<NQ_ + 1, 256, 0, stream>>>(W_v3, b_v, W_e, b_e, W_a, b_a,
                                           (float2*)ea2f);
    kB_scan<<<B_, 256, 0, stream>>>(q_data, r_data, init_mem, clutP,
                                    (const float2*)ea2f, reads);
    k4_fused<<<T_ / BT4A, 256, 0, stream>>>(q_data, q_tab, reads, W_sum, b_sum,
                                            W_ab, b_ab, W_th, b_th, W_disc, b_disc,
                                            (float*)d_out);
}

// Round 20
// 149.806 us; speedup vs baseline: 1.1370x; 1.1370x over previous
//
#include <hip/hip_runtime.h>
#include <math.h>

#define B_   256
#define S_   200
#define NQ_  400
#define K_   4
#define M_   50
#define KD_  50
#define VD_  200
#define FD_  50
#define T_   (B_*S_)   // 51200 tokens
#define NE_  ((NQ_+1)*K_)   // 1604 distinct (q,r) rows
#define CP_  52             // padded clut row stride (16B-aligned rows)

// ---------------------------------------------------------------------------
// kA1: corr LUT, PADDED rows [401][52] (cols 50,51 zeroed).
// ---------------------------------------------------------------------------
__global__ __launch_bounds__(256) void kA1_corrlut(
    const float* __restrict__ q_tab, const float* __restrict__ key_mem,
    const float* __restrict__ W_qk, const float* __restrict__ b_qk,
    float* __restrict__ clutP)
{
    const int wave = threadIdx.x >> 6;
    const int lane = threadIdx.x & 63;
    int qi = blockIdx.x * 4 + wave;
    const bool valid = (qi <= NQ_);
    if (qi > NQ_) qi = NQ_;

    __shared__ float sqk[4][KD_];
    const float* qe = q_tab + (size_t)qi * KD_;
    if (lane < KD_) {
        float acc = b_qk[lane];
#pragma unroll 10
        for (int k = 0; k < KD_; ++k)
            acc += qe[k] * W_qk[k * KD_ + lane];
        sqk[wave][lane] = tanhf(acc);
    }
    __syncthreads();

    float c = -INFINITY;
    if (lane < M_) {
        float acc = 0.0f;
#pragma unroll 10
        for (int k = 0; k < KD_; ++k)
            acc += sqk[wave][k] * key_mem[lane * KD_ + k];
        c = acc;
    }
    float mx = c;
#pragma unroll
    for (int off = 32; off; off >>= 1) mx = fmaxf(mx, __shfl_xor(mx, off));
    float e = (lane < M_) ? expf(c - mx) : 0.0f;
    float sm = e;
#pragma unroll
    for (int off = 32; off; off >>= 1) sm += __shfl_xor(sm, off);
    if (valid && lane < M_)  clutP[(size_t)qi * CP_ + lane] = e / sm;
    if (valid && lane >= M_ && lane < CP_) clutP[(size_t)qi * CP_ + lane] = 0.0f;
}

// ---------------------------------------------------------------------------
// kA2: fused (e,a) LUT as float2 [1604][200]. One block per q, 4 r-variants.
// ---------------------------------------------------------------------------
__global__ __launch_bounds__(256) void kA2_ealut(
    const float* __restrict__ W_v3, const float* __restrict__ b_v,
    const float* __restrict__ W_e, const float* __restrict__ b_e,
    const float* __restrict__ W_a, const float* __restrict__ b_a,
    float2* __restrict__ ea2)
{
    __shared__ __align__(16) float sV[VD_][4];   // [k][r]
    const int qi  = blockIdx.x;                  // 0..400
    const int tid = threadIdx.x;
    const float qm = (qi > 0) ? 1.0f : 0.0f;
    int idx = qi - 1;
    if (idx < 0) idx = 0;

    float wc[4][4];
#pragma unroll
    for (int r = 0; r < 4; ++r)
#pragma unroll
        for (int k = 0; k < 4; ++k) {
            float dist = fabsf((float)k - (float)r) / (float)(K_ - 1);
            float w = 1.0f - dist;
            wc[r][k] = (w > 0.0f) ? w : 0.0f;
        }

    if (tid < VD_) {
        float w3[4];
#pragma unroll
        for (int k = 0; k < 4; ++k)
            w3[k] = W_v3[((size_t)k * NQ_ + idx) * VD_ + tid];
        float bv = b_v[tid];
#pragma unroll
        for (int r = 0; r < 4; ++r) {
            float s = wc[r][0]*w3[0] + wc[r][1]*w3[1] + wc[r][2]*w3[2] + wc[r][3]*w3[3];
            sV[tid][r] = bv + qm * s;
        }
    }
    __syncthreads();

    if (tid < VD_) {
        const int c = tid;
        float accE[4] = {0.f,0.f,0.f,0.f}, accA[4] = {0.f,0.f,0.f,0.f};
#pragma unroll 4
        for (int k = 0; k < VD_; ++k) {
            float we = W_e[(size_t)k * VD_ + c];
            float wa = W_a[(size_t)k * VD_ + c];
            float4 v = *(const float4*)&sV[k][0];
            float vv[4] = {v.x, v.y, v.z, v.w};
#pragma unroll
            for (int r = 0; r < 4; ++r) {
                accE[r] = fmaf(vv[r], we, accE[r]);
                accA[r] = fmaf(vv[r], wa, accA[r]);
            }
        }
        const float be = b_e[c], ba = b_a[c];
#pragma unroll
        for (int r = 0; r < 4; ++r) {
            const size_t row = (size_t)qi * K_ + r;
            float ev = 1.0f / (1.0f + expf(-(accE[r] + be)));
            float av = tanhf(accA[r] + ba);
            ea2[row * VD_ + c] = make_float2(ev, av);
        }
    }
}

// ---------------------------------------------------------------------------
// kB v16 (declared floor ~102us): zero-barrier scan, deep (e,a) register
// banks, w via LDS wall + parity register banks.
// ---------------------------------------------------------------------------
__global__ __launch_bounds__(256, 1) void kB_scan(
    const int* __restrict__ q_data, const int* __restrict__ r_data,
    const float* __restrict__ init_mem, const float* __restrict__ clutP,
    const float2* __restrict__ ea2, float* __restrict__ reads)
{
    const int b   = blockIdx.x;
    const int tid = threadIdx.x;
    const int j   = tid;
    const bool act = (j < VD_);

    __shared__ int sE[S_];
    __shared__ __align__(16) float wall[S_][CP_];

    for (int i = tid; i < S_; i += 256)
        sE[i] = q_data[(size_t)b * S_ + i] * K_ + r_data[(size_t)b * S_ + i];
    __syncthreads();
    for (int i = tid; i < S_ * CP_; i += 256) {
        int row = i / CP_, col = i - row * CP_;
        wall[row][col] = clutP[(size_t)(sE[row] >> 2) * CP_ + col];
    }
    float mem[M_];
    if (act) {
#pragma unroll
        for (int m = 0; m < M_; ++m) mem[m] = init_mem[m * VD_ + j];
    }
    __syncthreads();   // LAST barrier

    float* rout = reads + (size_t)b * S_ * VD_;

    float eA[8], aA[8], eB[8], aB[8];
    if (act) {
#pragma unroll
        for (int h = 0; h < 8; ++h) {
            float2 v = ea2[(size_t)sE[h] * VD_ + j];
            eA[h] = v.x; aA[h] = v.y;
        }
#pragma unroll
        for (int h = 0; h < 8; ++h) {
            float2 v = ea2[(size_t)sE[8 + h] * VD_ + j];
            eB[h] = v.x; aB[h] = v.y;
        }
    }

    float4 wv0[13], wv1[13];
#pragma unroll
    for (int i = 0; i < 13; ++i) {
        wv0[i] = *(const float4*)&wall[0][4*i];
        wv1[i] = *(const float4*)&wall[1][4*i];
    }

#define SCAN_STEP(ST, EV, AV, WB)                                    \
    {                                                                \
        float ra = 0.f, rc = 0.f;                                    \
        _Pragma("unroll")                                            \
        for (int i_ = 0; i_ < 12; ++i_) {                            \
            const int m_ = 4 * i_;                                   \
            float4 w4 = WB[i_];                                      \
            ra = fmaf(w4.x, mem[m_], ra);                            \
            float t0 = fmaf(-(EV), mem[m_], (AV));                   \
            mem[m_] = fmaf(w4.x, t0, mem[m_]);                       \
            rc = fmaf(w4.y, mem[m_+1], rc);                          \
            float t1 = fmaf(-(EV), mem[m_+1], (AV));                 \
            mem[m_+1] = fmaf(w4.y, t1, mem[m_+1]);                   \
            ra = fmaf(w4.z, mem[m_+2], ra);                          \
            float t2 = fmaf(-(EV), mem[m_+2], (AV));                 \
            mem[m_+2] = fmaf(w4.z, t2, mem[m_+2]);                   \
            rc = fmaf(w4.w, mem[m_+3], rc);                          \
            float t3 = fmaf(-(EV), mem[m_+3], (AV));                 \
            mem[m_+3] = fmaf(w4.w, t3, mem[m_+3]);                   \
        }                                                            \
        {                                                            \
            float4 w4 = WB[12];                                      \
            ra = fmaf(w4.x, mem[48], ra);                            \
            float t0 = fmaf(-(EV), mem[48], (AV));                   \
            mem[48] = fmaf(w4.x, t0, mem[48]);                       \
            rc = fmaf(w4.y, mem[49], rc);                            \
            float t1 = fmaf(-(EV), mem[49], (AV));                   \
            mem[49] = fmaf(w4.y, t1, mem[49]);                       \
        }                                                            \
        if (act) rout[(size_t)(ST) * VD_ + j] = ra + rc;             \
        {                                                            \
            const int nr_ = ((ST) + 2 < S_) ? (ST) + 2 : S_ - 1;     \
            const float* wr_ = &wall[nr_][0];                        \
            _Pragma("unroll")                                        \
            for (int i_ = 0; i_ < 13; ++i_)                          \
                WB[i_] = *(const float4*)(wr_ + 4 * i_);             \
        }                                                            \
    }

    for (int k = 0; k < 12; ++k) {
        const int s0 = 16 * k;
        int eidAn[8];
#pragma unroll
        for (int h = 0; h < 8; ++h) {
            int idx = s0 + 16 + h; if (idx > S_ - 1) idx = S_ - 1;
            eidAn[h] = sE[idx];
        }
#pragma unroll
        for (int h = 0; h < 8; ++h) {
            if ((h & 1) == 0) { SCAN_STEP(s0 + h, eA[h], aA[h], wv0); }
            else              { SCAN_STEP(s0 + h, eA[h], aA[h], wv1); }
        }
        if (act) {
#pragma unroll
            for (int h = 0; h < 8; ++h) {
                float2 v = ea2[(size_t)eidAn[h] * VD_ + j];
                eA[h] = v.x; aA[h] = v.y;
            }
        }

        int eidBn[8];
#pragma unroll
        for (int h = 0; h < 8; ++h) {
            int idx = s0 + 24 + h; if (idx > S_ - 1) idx = S_ - 1;
            eidBn[h] = sE[idx];
        }
#pragma unroll
        for (int h = 0; h < 8; ++h) {
            if ((h & 1) == 0) { SCAN_STEP(s0 + 8 + h, eB[h], aB[h], wv0); }
            else              { SCAN_STEP(s0 + 8 + h, eB[h], aB[h], wv1); }
        }
        if (act) {
#pragma unroll
            for (int h = 0; h < 8; ++h) {
                float2 v = ea2[(size_t)eidBn[h] * VD_ + j];
                eB[h] = v.x; aB[h] = v.y;
            }
        }
    }
#pragma unroll
    for (int h = 0; h < 8; ++h) {
        if ((h & 1) == 0) { SCAN_STEP(192 + h, eA[h], aA[h], wv0); }
        else              { SCAN_STEP(192 + h, eA[h], aA[h], wv1); }
    }
#undef SCAN_STEP
}

// ---------------------------------------------------------------------------
// k4a: summary GEMM. Writes summary transposed summT[c][tok].
// ---------------------------------------------------------------------------
#define BT4A 40
__global__ __launch_bounds__(256) void k4a_summary(
    const int* __restrict__ q_data, const float* __restrict__ q_tab,
    const float* __restrict__ reads,
    const float* __restrict__ W_sum, const float* __restrict__ b_sum,
    float* __restrict__ summT)
{
    __shared__ __align__(16) float sAt[25][44];   // [kk][t], pad 44
    __shared__ __align__(16) float sW[25][52];
    __shared__ int sQ[BT4A];

    const int tid  = threadIdx.x;
    const int tok0 = blockIdx.x * BT4A;
    const int ty = tid / 25;        // 0..9 -> token group of 4
    const int tx = tid % 25;        // col pair
    const bool act = (tid < 250);
    const int t0 = ty * 4;

    if (tid < BT4A) sQ[tid] = q_data[tok0 + tid];

    float acc[4][2];
#pragma unroll
    for (int i = 0; i < 4; ++i) { acc[i][0] = 0.f; acc[i][1] = 0.f; }

    for (int kt = 0; kt < 250; kt += 25) {
        __syncthreads();
        for (int i = tid; i < BT4A * 25; i += 256) {
            int t = i / 25, kk = i % 25;
            float v;
            if (kt < VD_) v = reads[(size_t)(tok0 + t) * VD_ + kt + kk];
            else          v = q_tab[(size_t)sQ[t] * KD_ + (kt - VD_) + kk];
            sAt[kk][t] = v;
        }
        for (int i = tid; i < 25 * FD_; i += 256) {
            int kk = i / FD_, col = i % FD_;
            sW[kk][col] = W_sum[(size_t)(kt + kk) * FD_ + col];
        }
        __syncthreads();

        if (act) {
#pragma unroll 5
            for (int kk = 0; kk < 25; ++kk) {
                float2 w = *(const float2*)&sW[kk][2 * tx];
                float4 a0 = *(const float4*)&sAt[kk][t0];
                float av[4] = {a0.x, a0.y, a0.z, a0.w};
#pragma unroll
                for (int i = 0; i < 4; ++i) {
                    acc[i][0] = fmaf(av[i], w.x, acc[i][0]);
                    acc[i][1] = fmaf(av[i], w.y, acc[i][1]);
                }
            }
        }
    }

    if (act) {
        const float b0 = b_sum[2 * tx], b1 = b_sum[2 * tx + 1];
#pragma unroll
        for (int i = 0; i < 4; ++i) {
            const size_t tok = tok0 + t0 + i;
            summT[(size_t)(2 * tx)     * T_ + tok] = tanhf(acc[i][0] + b0);
            summT[(size_t)(2 * tx + 1) * T_ + tok] = tanhf(acc[i][1] + b1);
        }
    }
}

// ---------------------------------------------------------------------------
// k4b: per-token head. One thread per token.
// ---------------------------------------------------------------------------
__global__ __launch_bounds__(256) void k4b_head(
    const int* __restrict__ q_data, const float* __restrict__ q_tab,
    const float* __restrict__ summT,
    const float* __restrict__ W_ab, const float* __restrict__ b_ab,
    const float* __restrict__ W_th, const float* __restrict__ b_th,
    const float* __restrict__ W_disc, const float* __restrict__ b_disc,
    float* __restrict__ out)
{
    const int tok = blockIdx.x * 256 + threadIdx.x;
    const int q = q_data[tok];
    const float* qe = q_tab + (size_t)q * KD_;

    float v_ab = 0.f, v_d = 0.f, v_t0 = 0.f, v_t1 = 0.f, v_t2 = 0.f;
#pragma unroll 10
    for (int c = 0; c < FD_; ++c) {
        float s  = summT[(size_t)c * T_ + tok];
        float qv = qe[c];
        v_ab = fmaf(s,  W_ab[c],        v_ab);
        v_d  = fmaf(s,  W_disc[c],      v_d);
        v_d  = fmaf(qv, W_disc[FD_ + c], v_d);
        v_t0 = fmaf(qv, W_th[c * 3 + 0], v_t0);
        v_t1 = fmaf(qv, W_th[c * 3 + 1], v_t1);
        v_t2 = fmaf(qv, W_th[c * 3 + 2], v_t2);
    }

    float theta = 3.0f * (v_ab + b_ab[0]);
    float xd = v_d + b_disc[0];
    float alpha = fmaxf(xd, 0.0f) + log1pf(expf(-fabsf(xd)));
    float beta0 = tanhf(v_t0 + b_th[0]);
    float beta1 = tanhf(v_t1 + b_th[1]);
    float beta2 = tanhf(v_t2 + b_th[2]);
    float c1 = alpha * (theta - beta0);
    float c2 = c1 + alpha * (theta - beta1);
    float c3 = c2 + alpha * (theta - beta2);
    float mx = fmaxf(fmaxf(0.0f, c1), fmaxf(c2, c3));
    float e0 = expf(0.0f - mx), e1 = expf(c1 - mx),
          e2 = expf(c2 - mx), e3 = expf(c3 - mx);
    float s4 = e0 + e1 + e2 + e3;
    float4 o = make_float4(e0 / s4, e1 / s4, e2 / s4, e3 / s4);
    *(float4*)&out[(size_t)tok * 4] = o;
}

// ---------------------------------------------------------------------------
extern "C" void kernel_launch(void* const* d_in, const int* in_sizes, int n_in,
                              void* d_out, int out_size, void* d_ws, size_t ws_size,
                              hipStream_t stream) {
    const int*   q_data   = (const int*)  d_in[0];
    const int*   r_data   = (const int*)  d_in[1];
    const float* q_tab    = (const float*)d_in[2];
    const float* key_mem  = (const float*)d_in[3];
    const float* init_mem = (const float*)d_in[4];
    const float* W_qk     = (const float*)d_in[5];
    const float* b_qk     = (const float*)d_in[6];
    const float* W_v3     = (const float*)d_in[7];
    const float* b_v      = (const float*)d_in[8];
    const float* W_e      = (const float*)d_in[9];
    const float* b_e      = (const float*)d_in[10];
    const float* W_a      = (const float*)d_in[11];
    const float* b_a      = (const float*)d_in[12];
    const float* W_sum    = (const float*)d_in[13];
    const float* b_sum    = (const float*)d_in[14];
    const float* W_ab     = (const float*)d_in[15];
    const float* b_ab     = (const float*)d_in[16];
    const float* W_th     = (const float*)d_in[17];
    const float* b_th     = (const float*)d_in[18];
    const float* W_disc   = (const float*)d_in[19];
    const float* b_disc   = (const float*)d_in[20];

    float* ws    = (float*)d_ws;
    float* reads = ws;                                    // T*VD = 10.24M
    float* clutP = reads + (size_t)T_ * VD_;              // 401*52
    float* ea2f  = clutP + (size_t)(NQ_ + 1) * CP_;       // 1604*200*2 (float2)
    float* summT = ea2f + (size_t)NE_ * VD_ * 2;          // 50*T
    // total ~13.5M floats = 54 MB

    kA1_corrlut<<<(NQ_ + 4) / 4, 256, 0, stream>>>(q_tab, key_mem, W_qk, b_qk, clutP);
    kA2_ealut<<<NQ_ + 1, 256, 0, stream>>>(W_v3, b_v, W_e, b_e, W_a, b_a,
                                           (float2*)ea2f);
    kB_scan<<<B_, 256, 0, stream>>>(q_data, r_data, init_mem, clutP,
                                    (const float2*)ea2f, reads);
    k4a_summary<<<T_ / BT4A, 256, 0, stream>>>(q_data, q_tab, reads, W_sum, b_sum, summT);
    k4b_head<<<T_ / 256, 256, 0, stream>>>(q_data, q_tab, summT,
                                           W_ab, b_ab, W_th, b_th, W_disc, b_disc,
                                           (float*)d_out);
}